// Round 2
// baseline (91.967 us; speedup 1.0000x reference)
//
#include <hip/hip_runtime.h>

// Problem constants (match reference file)
#define B_ 8
#define N_ 1024
#define E_ 1536
#define FIN_ 64
#define FOUT_ 64
#define FEDGE_ 32
#define CAP_ 32   // adjacency slots per node; deg ~ Poisson(3), P(deg>32) ~ 0

// Workspace layout (byte offsets):
//   deg    [N]        int    @ 0       (4096 B)   -- per-node adjacency count (memset 0)
//   adj    [N*32]     int2   @ 4096    (262144 B) -- per-node list of (other_endpoint, edge_id)
//   lapuv  [E]        float  @ 266240  (6144 B)   -- lap[u,v] per edge
//   ew     [B*E]      float  @ 272384  (49152 B)  -- edges . edge_weight_vec
//   h      [B*N*64]   float  @ 321536  (2 MiB)    -- nodes @ W
#define WS_DEG   0
#define WS_ADJ   4096
#define WS_LAPUV 266240
#define WS_EW    272384
#define WS_H     321536

// Kernel 1 block-role split (all parts independent):
//   [0, 2048)      : node transform, 4 rows/block (transposed-W LDS, float4 dot)
//   [2048, 2144)   : incidence column-tiles -> endpoints (block-local LDS min/max,
//                    no global sentinels) + CSR insert + lap[u,v] precompute
//   [2144, 2192)   : edge weight dot products
#define NT_BLOCKS 2048
#define EX_BLOCKS 96
#define EW_BLOCKS 48
#define K1_BLOCKS (NT_BLOCKS + EX_BLOCKS + EW_BLOCKS)

__global__ __launch_bounds__(256) void fused_prep(
    const float* __restrict__ nodes,   // [B*N, 64]
    const float* __restrict__ W,       // [64, 64]
    const float* __restrict__ inc,     // [N, E]
    const float* __restrict__ edges,   // [B*E, 32]
    const float* __restrict__ evec,    // [32]
    const float* __restrict__ lap,     // [N, N]
    int*   __restrict__ deg,           // [N] zeroed by memset
    int2*  __restrict__ adj,           // [N*CAP_]
    float* __restrict__ lapuv,         // [E]
    float* __restrict__ ew,            // [B*E]
    float* __restrict__ h)             // [B*N, 64]
{
    // Wt stride 68 floats: quad-bank stride 17 == 1 (mod 8) -> conflict-free b128 reads.
    __shared__ float Wt[FOUT_ * 68];   // Wt[f*68+k] = W[k*64+f]; 17408 B
    __shared__ float rows[4 * FIN_];   // 1 KiB
    __shared__ int smin[16], smax[16];
    const int blk = blockIdx.x;
    const int tid = threadIdx.x;

    if (blk < NT_BLOCKS) {
        // ---- h = nodes @ W (4 rows per block) ----
#pragma unroll
        for (int idx = tid; idx < FIN_ * FOUT_; idx += 256) {
            Wt[(idx & 63) * 68 + (idx >> 6)] = W[idx];   // transpose into LDS
        }
        rows[tid] = nodes[(size_t)blk * 256 + tid];      // 4 rows, coalesced
        __syncthreads();
        const int r = tid >> 6;        // row within block (wave-uniform)
        const int f = tid & 63;        // output feature
        const float4* wp = (const float4*)&Wt[f * 68];   // 272 B row -> 16B aligned
        const float4* xp = (const float4*)&rows[r * FIN_];
        float acc = 0.0f;
#pragma unroll
        for (int q = 0; q < FIN_ / 4; ++q) {
            const float4 w = wp[q];    // per-lane b128, conflict-free
            const float4 x = xp[q];    // wave-uniform broadcast b128
            acc += w.x * x.x + w.y * x.y + w.z * x.z + w.w * x.w;
        }
        h[(size_t)blk * 256 + tid] = acc;                // coalesced (FIN_==FOUT_)
    } else if (blk < NT_BLOCKS + EX_BLOCKS) {
        // ---- endpoints of 16 columns of inc, entirely block-local ----
        const int c0 = (blk - NT_BLOCKS) * 16;           // base edge/column
        if (tid < 16) { smin[tid] = 0x7fffffff; smax[tid] = -1; }
        __syncthreads();
        const int col = tid & 15;
        const int rb  = tid >> 4;                        // row phase 0..15
        int lmin = 0x7fffffff, lmax = -1;
        const float* p = inc + (size_t)rb * E_ + c0 + col;
#pragma unroll 4
        for (int i = 0; i < N_ / 16; ++i) {              // rows rb, rb+16, ...
            if (p[(size_t)i * 16 * E_] != 0.0f) {
                const int r = rb + 16 * i;
                lmin = min(lmin, r);
                lmax = max(lmax, r);
            }
        }
        if (lmax >= 0) {                                 // <=2 hits per column total
            atomicMin(&smin[col], lmin);
            atomicMax(&smax[col], lmax);
        }
        __syncthreads();
        if (tid < 16) {
            const int e = c0 + tid;
            const int u = smin[tid];                     // guaranteed u < v (src != dst)
            const int v = smax[tid];
            const int pu = atomicAdd(&deg[u], 1);
            if (pu < CAP_) adj[u * CAP_ + pu] = make_int2(v, e);
            const int pv = atomicAdd(&deg[v], 1);
            if (pv < CAP_) adj[v * CAP_ + pv] = make_int2(u, e);
            lapuv[e] = lap[(size_t)u * N_ + v];
        }
    } else {
        // ---- ew[b,e] = edges[b,e,:] . evec ----
        const int t = (blk - NT_BLOCKS - EX_BLOCKS) * 256 + tid;   // [0, B*E)
        const float4* ep = (const float4*)(edges + (size_t)t * FEDGE_);
        float s = 0.0f;
#pragma unroll
        for (int j = 0; j < FEDGE_ / 4; ++j) {
            const float4 a = ep[j];
            s += a.x * evec[4 * j + 0] + a.y * evec[4 * j + 1]
               + a.z * evec[4 * j + 2] + a.w * evec[4 * j + 3];
        }
        ew[t] = s;
    }
}

// ---- Kernel 2: pure gather, one wave per (b,node). No atomics, out written once. ----
// out[b,u,:] = sum_{e=(u,v)} ew[b,e]*lap[u,v]*h[b,v,:]  +  lap[u,u]*(sum ew)*h[b,u,:]
__global__ __launch_bounds__(256) void gather_nodes(
    const int*   __restrict__ deg,
    const int2*  __restrict__ adj,
    const float* __restrict__ lapuv,
    const float* __restrict__ ew,
    const float* __restrict__ lap,
    const float* __restrict__ h,
    float*       __restrict__ out)
{
    const int wid  = (blockIdx.x * 256 + threadIdx.x) >> 6;  // (b,u) pair, exact grid
    const int lane = threadIdx.x & 63;
    const int b = wid >> 10;             // N_ == 1024
    const int u = wid & (N_ - 1);
    int d = deg[u];
    if (d > CAP_) d = CAP_;
    const float* hb  = h + (size_t)b * N_ * FOUT_;
    const float* ewb = ew + (size_t)b * E_;
    float acc = 0.0f, esum = 0.0f;
    for (int j = 0; j < d; ++j) {        // wave-uniform trip count (all lanes same u)
        const int2 a = adj[u * CAP_ + j];                  // broadcast
        const float s = ewb[a.y];                          // broadcast
        acc  += s * lapuv[a.y] * hb[(size_t)a.x * FOUT_ + lane];
        esum += s;
    }
    const float ldiag = lap[(size_t)u * (N_ + 1)];         // lap[u,u], broadcast
    out[(size_t)wid * FOUT_ + lane] =
        acc + esum * ldiag * hb[(size_t)u * FOUT_ + lane]; // coalesced, single write
}

extern "C" void kernel_launch(void* const* d_in, const int* in_sizes, int n_in,
                              void* d_out, int out_size, void* d_ws, size_t ws_size,
                              hipStream_t stream) {
    const float* nodes = (const float*)d_in[0];   // [B,N,64]
    const float* edges = (const float*)d_in[1];   // [B,E,32]
    const float* W     = (const float*)d_in[2];   // [64,64]
    const float* evec  = (const float*)d_in[3];   // [32]
    const float* inc   = (const float*)d_in[4];   // [N,E]
    const float* lap   = (const float*)d_in[5];   // [N,N]
    float* out = (float*)d_out;

    char* ws = (char*)d_ws;
    int*   deg   = (int*)(ws + WS_DEG);
    int2*  adj   = (int2*)(ws + WS_ADJ);
    float* lapuv = (float*)(ws + WS_LAPUV);
    float* ewb   = (float*)(ws + WS_EW);
    float* h     = (float*)(ws + WS_H);

    // Only the 4 KiB degree counters need zeroing (endpoint extraction is now
    // block-local; no global sentinels).
    hipMemsetAsync(deg, 0, N_ * sizeof(int), stream);

    fused_prep<<<K1_BLOCKS, 256, 0, stream>>>(nodes, W, inc, edges, evec, lap,
                                              deg, adj, lapuv, ewb, h);
    gather_nodes<<<(B_ * N_ * FOUT_) / 256, 256, 0, stream>>>(deg, adj, lapuv, ewb,
                                                              lap, h, out);
}

// Round 3
// 89.688 us; speedup vs baseline: 1.0254x; 1.0254x over previous
//
#include <hip/hip_runtime.h>

// Problem constants (match reference file)
#define B_ 8
#define N_ 1024
#define E_ 1536
#define FIN_ 64
#define FOUT_ 64
#define FEDGE_ 32
#define CAP_ 32   // adjacency slots per node; deg ~ Poisson(3), P(deg>32) ~ 0

// Workspace layout (byte offsets):
//   deg [N]       int  @ 0    (4096 B)   -- per-node adjacency count (memset 0)
//   adj [N*CAP_]  int2 @ 4096 (262144 B) -- per-node list of (other_endpoint, edge_id)
#define WS_DEG 0
#define WS_ADJ 4096

// ---- Kernel A: CSR build. One block per 16 incidence columns (edges). ----
// 16 columns x 4B = 64 B = exactly one cache line per row segment; min/max of the
// two nonzero rows found block-locally in LDS, then CSR-inserted (global atomics
// only on deg, ~2 per edge).
__global__ __launch_bounds__(512) void build_csr(
    const float* __restrict__ inc,   // [N, E]
    int*  __restrict__ deg,          // [N] zeroed by memset
    int2* __restrict__ adj)          // [N*CAP_]
{
    __shared__ int smin[16], smax[16];
    const int tid = threadIdx.x;
    const int c0 = blockIdx.x * 16;
    if (tid < 16) { smin[tid] = 0x7fffffff; smax[tid] = -1; }
    __syncthreads();
    const int col = tid & 15;
    const int rb  = tid >> 4;                        // row phase 0..31
    int lmin = 0x7fffffff, lmax = -1;
    const float* p = inc + (size_t)rb * E_ + c0 + col;
#pragma unroll 8
    for (int i = 0; i < N_ / 32; ++i) {              // rows rb, rb+32, ...
        if (p[(size_t)i * 32 * E_] != 0.0f) {
            const int r = rb + 32 * i;
            lmin = min(lmin, r);
            lmax = max(lmax, r);
        }
    }
    if (lmax >= 0) {                                 // <=2 hits per column total
        atomicMin(&smin[col], lmin);
        atomicMax(&smax[col], lmax);
    }
    __syncthreads();
    if (tid < 16) {
        const int e = c0 + tid;
        const int u = smin[tid];                     // u < v guaranteed (src != dst)
        const int v = smax[tid];
        const int pu = atomicAdd(&deg[u], 1);
        if (pu < CAP_) adj[u * CAP_ + pu] = make_int2(v, e);
        const int pv = atomicAdd(&deg[v], 1);
        if (pv < CAP_) adj[v * CAP_ + pv] = make_int2(u, e);
    }
}

// ---- Kernel B: everything else, one wave per (b,u). ----
// By linearity: out[b,u,:] = xagg @ W, where
//   xagg = sum_{e=(u,v)} ew[b,e]*lap[u,v]*nodes[b,v,:]
//        + (sum_e ew[b,e])*lap[u,u]*nodes[b,u,:]
// ew is recomputed on the fly (32-lane partial + shfl-xor reduce). No h buffer,
// no atomics, out written exactly once, coalesced.
__global__ __launch_bounds__(256) void gather_all(
    const float* __restrict__ nodes,  // [B*N, 64]
    const float* __restrict__ edges,  // [B*E, 32]
    const float* __restrict__ W,      // [64, 64]
    const float* __restrict__ evec,   // [32]
    const float* __restrict__ lap,    // [N, N]
    const int*   __restrict__ deg,
    const int2*  __restrict__ adj,
    float*       __restrict__ out)    // [B*N, 64]
{
    // Wt stride 68 floats: 16B-unit stride 17 == 1 (mod 8) -> conflict-free b128.
    __shared__ float Wt[FOUT_ * 68];   // Wt[f*68+k] = W[k*64+f]; 17408 B
    __shared__ float xs[4][FIN_];      // per-wave aggregated input row
    const int tid = threadIdx.x;
#pragma unroll
    for (int idx = tid; idx < FIN_ * FOUT_; idx += 256)
        Wt[(idx & 63) * 68 + (idx >> 6)] = W[idx];   // coalesced global read

    const int w    = tid >> 6;
    const int lane = tid & 63;
    const int wid  = blockIdx.x * 4 + w;             // (b,u), exact grid
    const int b = wid >> 10;                         // N_ == 1024
    const int u = wid & (N_ - 1);
    int d = deg[u];
    if (d > CAP_) d = CAP_;
    const float* nb = nodes + (size_t)b * N_ * FIN_;
    const float  ev = evec[lane & 31];
    float xagg = 0.0f, esum = 0.0f;
    for (int j = 0; j < d; ++j) {                    // wave-uniform trip count
        const int2 a = adj[u * CAP_ + j];            // broadcast 8B
        // ew[b,e]: lanes 0..31 and 32..63 each hold a copy of the 32 partials
        float pe = edges[((size_t)b * E_ + a.y) * FEDGE_ + (lane & 31)] * ev;
        pe += __shfl_xor(pe, 16);
        pe += __shfl_xor(pe, 8);
        pe += __shfl_xor(pe, 4);
        pe += __shfl_xor(pe, 2);
        pe += __shfl_xor(pe, 1);                     // all 64 lanes: full sum
        const float luv = lap[(size_t)u * N_ + a.x]; // broadcast 4B
        xagg += pe * luv * nb[(size_t)a.x * FIN_ + lane];  // coalesced 256B
        esum += pe;
    }
    const float ldiag = lap[(size_t)u * (N_ + 1)];   // lap[u,u]
    xagg += esum * ldiag * nb[(size_t)u * FIN_ + lane];

    xs[w][lane] = xagg;
    __syncthreads();                                 // covers Wt + xs
    const float4* xp = (const float4*)&xs[w][0];     // wave-uniform broadcast b128
    const float4* wp = (const float4*)&Wt[lane * 68];// per-lane b128, conflict-free
    float acc = 0.0f;
#pragma unroll
    for (int q = 0; q < FIN_ / 4; ++q) {
        const float4 x  = xp[q];
        const float4 wv = wp[q];
        acc += x.x * wv.x + x.y * wv.y + x.z * wv.z + x.w * wv.w;
    }
    out[(size_t)wid * FOUT_ + lane] = acc;           // coalesced, single write
}

extern "C" void kernel_launch(void* const* d_in, const int* in_sizes, int n_in,
                              void* d_out, int out_size, void* d_ws, size_t ws_size,
                              hipStream_t stream) {
    const float* nodes = (const float*)d_in[0];   // [B,N,64]
    const float* edges = (const float*)d_in[1];   // [B,E,32]
    const float* W     = (const float*)d_in[2];   // [64,64]
    const float* evec  = (const float*)d_in[3];   // [32]
    const float* inc   = (const float*)d_in[4];   // [N,E]
    const float* lap   = (const float*)d_in[5];   // [N,N]
    float* out = (float*)d_out;

    char* ws = (char*)d_ws;
    int*  deg = (int*)(ws + WS_DEG);
    int2* adj = (int2*)(ws + WS_ADJ);

    hipMemsetAsync(deg, 0, N_ * sizeof(int), stream);   // 4 KiB only
    build_csr<<<E_ / 16, 512, 0, stream>>>(inc, deg, adj);
    gather_all<<<(B_ * N_) / 4, 256, 0, stream>>>(nodes, edges, W, evec, lap,
                                                  deg, adj, out);
}